// Round 12
// baseline (123.033 us; speedup 1.0000x reference)
//
#include <hip/hip_runtime.h>
#include <math.h>

#define Wd 256
#define Hd 256
#define KW 11
#define OUT_R 24              // output rows per block; stream 36 = 18 pair-steps
#define RING 12               // slot = (2*jp+c)%12, chunk-independent (6 steps/chunk)
#define BLOCK 256

typedef float v2f __attribute__((ext_vector_type(2)));

__device__ __forceinline__ float rfl(float v) {
    return __int_as_float(__builtin_amdgcn_readfirstlane(__float_as_int(v)));
}

// lgkmcnt-only barrier (R2/R5): LDS handoff without draining global prefetch.
__device__ __forceinline__ void barrier_lds_only() {
    asm volatile("s_waitcnt lgkmcnt(0)\n\ts_barrier" ::: "memory");
}

// R12: HALVE THE BARRIER-PERIOD COUNT (13 -> 6).
//
// Ledger (~42us invariant): barrier flavor, residency, prefetch depth (-4%),
// skew, step size, LDS layout, bank conflicts, memory residency (L3==HBM),
// instruction count (R9: fewer inst = slower), wave privatization, atomics
// (R11). Recount: EVERY variant had 13-15 barrier periods/block (R7 had 2
// bars x 7 emits, not fewer). 42us/13 periods ~= 7700 cyc/period vs ~600 cyc
// of work -- the fixed per-period machinery (all-wave arrival + post-barrier
// refill at ~3 block-streams/CU) is the one never-varied suspect.
//
// Structure: emits grouped in pairs. Period = {vconv stepA -> bufpair slotA,
// vconv stepB -> slotB, ONE barrier, hconv A + hconv B (4 output rows)}.
// Two buffer-pairs alternate across periods; write-after-read safety is
// provided by the NEXT period's barrier (a wave cannot pass barrier g+1
// while any wave is still reading period g's pair). 6 barriers/block.
//
// Geometry: OUT_R=24, ghbase = band*24-7, emit chunks ch>=1 -> k=6ch+jp,
// out rows 2k-12,2k-11. Slot math identical to R5: (2jp+2+m)%12.
// launch_bounds(256,4) as R5 (VGPR 48 proven; arg2>4 spills -- R1/R3).
__global__ __launch_bounds__(BLOCK, 4) void ssim_pair_kernel(
    const float* __restrict__ img1, const float* __restrict__ img2,
    const float* __restrict__ window, float* __restrict__ ws)
{
    // [bufpair][slot A/B][row 0/1][136]; halo cells zeroed in prologue.
    __shared__ __align__(16) float4 rbE[2][2][2][136];
    __shared__ __align__(16) float4 rbO[2][2][2][136];   // 34.8 KB
    __shared__ float red[BLOCK / 64];

    const float C1 = 1e-4f, C2 = 9e-4f;
    const int t = threadIdx.x;
    const int band = blockIdx.x;     // 0..10 (band 10 partial: 16 rows)
    const int plane = blockIdx.y;    // 0..143
    const float* __restrict__ p1 = img1 + (size_t)plane * (Hd * Wd);
    const float* __restrict__ p2 = img2 + (size_t)plane * (Hd * Wd);

    // Separable 1D weights (win2d = a outer a, sum a = 1); pin to SGPRs.
    float wl[KW];
    {
        float c = sqrtf(window[5 * KW + 5]);
        #pragma unroll
        for (int k = 0; k < KW; ++k)
            wl[k] = rfl(window[k * KW + 5] / c);
    }

    // Zero column-halo cells of all 8 row-buffers (2 pairs x 2 slots x 2
    // rows): E idx 0,1,130,131,132 ; O idx 0,1,2,131,132. 8 threads.
    if (t < 8) {
        int bp = t >> 2, sl = (t >> 1) & 1, row = t & 1;
        float4 z = make_float4(0.f, 0.f, 0.f, 0.f);
        rbE[bp][sl][row][0] = z; rbE[bp][sl][row][1] = z;
        rbE[bp][sl][row][130] = z; rbE[bp][sl][row][131] = z; rbE[bp][sl][row][132] = z;
        rbO[bp][sl][row][0] = z; rbO[bp][sl][row][1] = z; rbO[bp][sl][row][2] = z;
        rbO[bp][sl][row][131] = z; rbO[bp][sl][row][132] = z;
    }

    const int ghbase = band * OUT_R - 7;   // global row of stream index 0

    v2f rXY[RING], rQP[RING];
    float acc = 0.f;

    // 2-deep prefetch pipeline (R5): cur = this step's pair, nxt = next.
    float cx0, cy0, cx1, cy1;
    float nx0, ny0, nx1, ny1;
    {
        int g0 = ghbase, g1 = ghbase + 1;
        cx0 = ((unsigned)g0 < (unsigned)Hd) ? p1[(g0 << 8) + t] : 0.f;
        cy0 = ((unsigned)g0 < (unsigned)Hd) ? p2[(g0 << 8) + t] : 0.f;
        cx1 = ((unsigned)g1 < (unsigned)Hd) ? p1[(g1 << 8) + t] : 0.f;
        cy1 = ((unsigned)g1 < (unsigned)Hd) ? p2[(g1 << 8) + t] : 0.f;
        int g2 = ghbase + 2, g3 = ghbase + 3;
        nx0 = ((unsigned)g2 < (unsigned)Hd) ? p1[(g2 << 8) + t] : 0.f;
        ny0 = ((unsigned)g2 < (unsigned)Hd) ? p2[(g2 << 8) + t] : 0.f;
        nx1 = ((unsigned)g3 < (unsigned)Hd) ? p1[(g3 << 8) + t] : 0.f;
        ny1 = ((unsigned)g3 < (unsigned)Hd) ? p2[(g3 << 8) + t] : 0.f;
    }

    #pragma unroll 1
    for (int ch = 0; ch < 3; ++ch) {       // k = 6*ch + jp, pair-steps 0..17
        #pragma unroll
        for (int jp = 0; jp < 6; ++jp) {
            const int i0 = 12 * ch + 2 * jp;        // = 2k, uniform
            const int s0 = (2 * jp) % RING;         // STATIC slot
            const int s1 = (2 * jp + 1) % RING;     // STATIC slot

            // ring insert stream rows 2k, 2k+1 (consume cur)
            {
                v2f v; v.x = cx0; v.y = cy0; rXY[s0] = v;
                v2f q; q.x = fmaf(cx0, cx0, cy0 * cy0); q.y = cx0 * cy0; rQP[s0] = q;
                v2f v2; v2.x = cx1; v2.y = cy1; rXY[s1] = v2;
                v2f q2; q2.x = fmaf(cx1, cx1, cy1 * cy1); q2.y = cx1 * cy1; rQP[s1] = q2;
            }
            // rotate pipeline, issue loads 2 steps ahead (rows 2k+4, 2k+5)
            cx0 = nx0; cy0 = ny0; cx1 = nx1; cy1 = ny1;
            if (i0 + 4 < 36) {
                int g0 = ghbase + i0 + 4, g1 = ghbase + i0 + 5;
                nx0 = ((unsigned)g0 < (unsigned)Hd) ? p1[(g0 << 8) + t] : 0.f;
                ny0 = ((unsigned)g0 < (unsigned)Hd) ? p2[(g0 << 8) + t] : 0.f;
                nx1 = ((unsigned)g1 < (unsigned)Hd) ? p1[(g1 << 8) + t] : 0.f;
                ny1 = ((unsigned)g1 < (unsigned)Hd) ? p2[(g1 << 8) + t] : 0.f;
            }

            if (ch >= 1) {   // emit step: out rows 2k-12, 2k-11
                // vertical 11-tap conv, STATIC slots (2jp+2+m)%12,(2jp+3+m)%12
                v2f vAB0, vQP0, vAB1, vQP1;
                vAB0.x = vAB0.y = vQP0.x = vQP0.y = 0.f;
                vAB1.x = vAB1.y = vQP1.x = vQP1.y = 0.f;
                #pragma unroll
                for (int m = 0; m < KW; ++m) {
                    const int sa = (2 * jp + 2 + m) % RING;
                    const int sb = (2 * jp + 3 + m) % RING;
                    float w = wl[m];
                    vAB0 += w * rXY[sa];  vQP0 += w * rQP[sa];
                    vAB1 += w * rXY[sb];  vQP1 += w * rQP[sb];
                }
                const int wbp = (ch + (jp >> 1)) & 1;   // buffer-pair (uniform)
                const int sl  = jp & 1;                 // slot within pair (STATIC)
                const int half = t >> 1;
                if (t & 1) {
                    rbO[wbp][sl][0][half + 3] = make_float4(vAB0.x, vAB0.y, vQP0.x, vQP0.y);
                    rbO[wbp][sl][1][half + 3] = make_float4(vAB1.x, vAB1.y, vQP1.x, vQP1.y);
                } else {
                    rbE[wbp][sl][0][half + 2] = make_float4(vAB0.x, vAB0.y, vQP0.x, vQP0.y);
                    rbE[wbp][sl][1][half + 2] = make_float4(vAB1.x, vAB1.y, vQP1.x, vQP1.y);
                }

                if (sl == 1) {   // end of period: ONE barrier, then both hconvs
                    barrier_lds_only();
                    const int orowA = band * OUT_R + 2 * (6 * ch + jp - 1) - 12;
                    const int r = t >> 7, cp = t & 127;   // out cols 2cp, 2cp+1
                    #pragma unroll
                    for (int ss = 0; ss < 2; ++ss) {      // slot A rows, slot B rows
                        if (orowA + 2 * ss < Hd) {
                            const float4* bE = &rbE[wbp][ss][r][cp];
                            const float4* bO = &rbO[wbp][ss][r][cp];
                            v2f a0, q0, a1, q1;
                            a0.x = a0.y = q0.x = q0.y = 0.f;
                            a1.x = a1.y = q1.x = q1.y = 0.f;
                            #pragma unroll
                            for (int k = 0; k < 6; ++k) {
                                float4 vO = bO[k];                 // ds_read_b128
                                v2f oab; oab.x = vO.x; oab.y = vO.y;
                                v2f oqp; oqp.x = vO.z; oqp.y = vO.w;
                                a0 += wl[2 * k] * oab;  q0 += wl[2 * k] * oqp;
                                if (k >= 1) { a1 += wl[2 * k - 1] * oab;  q1 += wl[2 * k - 1] * oqp; }
                                float4 vE = bE[k];                 // ds_read_b128
                                v2f eab; eab.x = vE.x; eab.y = vE.y;
                                v2f eqp; eqp.x = vE.z; eqp.y = vE.w;
                                a1 += wl[2 * k] * eab;  q1 += wl[2 * k] * eqp;
                                if (k <= 4) { a0 += wl[2 * k + 1] * eab;  q0 += wl[2 * k + 1] * eqp; }
                            }
                            {
                                float mu1 = a0.x, mu2 = a0.y, sq = q0.x, sp = q0.y;
                                float mu12 = mu1 * mu2;
                                float musum = mu1 * mu1 + mu2 * mu2;
                                float num = (2.f * mu12 + C1) * (2.f * (sp - mu12) + C2);
                                float den = (musum + C1) * ((sq - musum) + C2);
                                acc += num * __builtin_amdgcn_rcpf(den);
                            }
                            {
                                float mu1 = a1.x, mu2 = a1.y, sq = q1.x, sp = q1.y;
                                float mu12 = mu1 * mu2;
                                float musum = mu1 * mu1 + mu2 * mu2;
                                float num = (2.f * mu12 + C1) * (2.f * (sp - mu12) + C2);
                                float den = (musum + C1) * ((sq - musum) + C2);
                                acc += num * __builtin_amdgcn_rcpf(den);
                            }
                        }
                    }
                }
            }
        }
    }

    // --- block reduction -> per-block partial in workspace (R11) ---
    #pragma unroll
    for (int off = 32; off > 0; off >>= 1)
        acc += __shfl_down(acc, off, 64);
    int wave = t >> 6;
    if ((t & 63) == 0) red[wave] = acc;
    barrier_lds_only();
    if (t == 0)
        ws[blockIdx.y * gridDim.x + blockIdx.x] =
            red[0] + red[1] + red[2] + red[3];
}

// Tiny second pass: reduce the per-block partials, write the scalar.
__global__ __launch_bounds__(256) void ssim_reduce_kernel(
    const float* __restrict__ ws, float* __restrict__ out, float scale, int n)
{
    __shared__ float red[4];
    const int t = threadIdx.x;
    float s = 0.f;
    for (int i = t; i < n; i += 256) s += ws[i];
    #pragma unroll
    for (int off = 32; off > 0; off >>= 1)
        s += __shfl_down(s, off, 64);
    if ((t & 63) == 0) red[t >> 6] = s;
    __syncthreads();
    if (t == 0)
        out[0] = 1.0f + (red[0] + red[1] + red[2] + red[3]) * scale;
}

extern "C" void kernel_launch(void* const* d_in, const int* in_sizes, int n_in,
                              void* d_out, int out_size, void* d_ws, size_t ws_size,
                              hipStream_t stream) {
    const float* img1   = (const float*)d_in[0];
    const float* img2   = (const float*)d_in[1];
    const float* window = (const float*)d_in[2];
    float* out = (float*)d_out;
    float* ws  = (float*)d_ws;

    const int planes = 16 * 9;                     // 144
    const int bands = (Hd + OUT_R - 1) / OUT_R;    // 11 (last band 16 rows)
    const int nblocks = planes * bands;            // 1584 partials in d_ws

    const float scale = -(float)(1.0 / ((double)planes * Hd * Wd));
    dim3 grid(bands, planes);
    ssim_pair_kernel<<<grid, BLOCK, 0, stream>>>(img1, img2, window, ws);
    ssim_reduce_kernel<<<1, 256, 0, stream>>>(ws, out, scale, nblocks);
}